// Round 5
// baseline (386.291 us; speedup 1.0000x reference)
//
#include <hip/hip_runtime.h>
#include <hip/hip_bf16.h>

// Problem constants (B,S,D,H,DK) = (2,2048,1024,16,64), fp32 in/out.
#define NB 2
#define NS 2048
#define ND 1024
#define NH 16
#define NDK 64

typedef __attribute__((ext_vector_type(4))) float f32x4;
typedef __attribute__((ext_vector_type(8))) short bf16x8;
typedef __attribute__((ext_vector_type(4))) short bf16x4;

__device__ __forceinline__ f32x4 mfma16(bf16x8 a, bf16x8 b, f32x4 c) {
  return __builtin_amdgcn_mfma_f32_16x16x32_bf16(a, b, c, 0, 0, 0);
}

// async global->LDS, 16B per lane (dest = wave-uniform base + lane*16)
__device__ __forceinline__ void async16(const void* g, void* l) {
  __builtin_amdgcn_global_load_lds(
      (const __attribute__((address_space(1))) unsigned int*)g,
      (__attribute__((address_space(3))) unsigned int*)l, 16, 0, 0);
}

// fp32 -> bf16 RNE
__device__ __forceinline__ short f2b(float f) {
  union { float f; unsigned u; } v;
  v.f = f;
  unsigned r = v.u + 0x7FFFu + ((v.u >> 16) & 1u);
  return (short)(r >> 16);
}

// packed fp32x2 -> bf16x2 (RNE) via v_perm_b32
__device__ __forceinline__ unsigned f2b2(float a, float b) {
  unsigned ua = __float_as_uint(a), ub = __float_as_uint(b);
  ua = ua + 0x7FFFu + ((ua >> 16) & 1u);
  ub = ub + 0x7FFFu + ((ub >> 16) & 1u);
  return __builtin_amdgcn_perm(ub, ua, 0x07060302);  // {ua.hi16, ub.hi16}
}

// raw v_exp_f32 — inputs here are either in [-40, 40] or -1e30 (masked -> 0),
// so the OCML denorm-fixup sequence exp2f expands to is unnecessary.
__device__ __forceinline__ float fast_exp2(float x) {
#if __has_builtin(__builtin_amdgcn_exp2f)
  return __builtin_amdgcn_exp2f(x);
#else
  return exp2f(x);
#endif
}

// pipeline barriers: wait only the N-oldest outstanding staging loads, then
// barrier (per-thread own-loads-complete + barrier => whole tile complete).
__device__ __forceinline__ void pipe_barrier4() {
  asm volatile("s_waitcnt vmcnt(4)\n\ts_barrier" ::: "memory");
}
__device__ __forceinline__ void pipe_barrier0() {
  asm volatile("s_waitcnt vmcnt(0)\n\ts_barrier" ::: "memory");
}

// ---------------------------------------------------------------------------
// prep: cast x and weights to bf16 (float4-vectorized), RoPE tables [S][32]
// ---------------------------------------------------------------------------
__global__ void prep_k(const float* __restrict__ x,
                       const float* __restrict__ Wq, const float* __restrict__ Wk,
                       const float* __restrict__ Wv, const float* __restrict__ Wo,
                       const int* __restrict__ pos,
                       short* __restrict__ xb,
                       short* __restrict__ wqb, short* __restrict__ wkb,
                       short* __restrict__ wvb, short* __restrict__ wob,
                       float* __restrict__ cosT, float* __restrict__ sinT) {
  const int stride = gridDim.x * blockDim.x;
  const int tid = blockIdx.x * blockDim.x + threadIdx.x;
  const float4* x4 = (const float4*)x;
  for (int i = tid; i < NB * NS * ND / 4; i += stride) {
    float4 v = x4[i];
    bf16x4 p; p[0] = f2b(v.x); p[1] = f2b(v.y); p[2] = f2b(v.z); p[3] = f2b(v.w);
    *(bf16x4*)(xb + i * 4) = p;
  }
  const float4* q4 = (const float4*)Wq; const float4* k4 = (const float4*)Wk;
  const float4* v4 = (const float4*)Wv; const float4* o4 = (const float4*)Wo;
  for (int i = tid; i < ND * ND / 4; i += stride) {
    float4 a = q4[i], b = k4[i], c = v4[i], d = o4[i];
    bf16x4 pa, pb, pc, pd;
    pa[0]=f2b(a.x); pa[1]=f2b(a.y); pa[2]=f2b(a.z); pa[3]=f2b(a.w);
    pb[0]=f2b(b.x); pb[1]=f2b(b.y); pb[2]=f2b(b.z); pb[3]=f2b(b.w);
    pc[0]=f2b(c.x); pc[1]=f2b(c.y); pc[2]=f2b(c.z); pc[3]=f2b(c.w);
    pd[0]=f2b(d.x); pd[1]=f2b(d.y); pd[2]=f2b(d.z); pd[3]=f2b(d.w);
    *(bf16x4*)(wqb + i*4) = pa; *(bf16x4*)(wkb + i*4) = pb;
    *(bf16x4*)(wvb + i*4) = pc; *(bf16x4*)(wob + i*4) = pd;
  }
  for (int i = tid; i < NS * 32; i += stride) {
    const int s = i >> 5, j = i & 31;
    const float inv = 1.0f / powf(10000.0f, (float)j * (1.0f / 32.0f));
    const float a = (float)pos[s] * inv;
    cosT[i] = cosf(a);
    sinT[i] = sinf(a);
  }
}

// ---------------------------------------------------------------------------
// GEMM: C[m,n] = sum_k A[m,k]*W[n,k];  M=4096, K=1024, bf16 MFMA.
// m97 wave shape: 256 threads, 4 waves (2x2), each wave 4x4 frags of 16x16
// (16 MFMA per 8 ds_read_b128). 128x128 tile, BK=32, TRIPLE-buffered with
// vmcnt(4) pipeline barriers (loads get ~2 compute phases), unrolled x3 so
// the buffer index is compile-time. 48 KB LDS (reused by V^T transpose).
// XCD decode: xcd=id&7 owns 4 m-panels; n streams (A stays L2-resident).
// ---------------------------------------------------------------------------
__global__ __launch_bounds__(256, 3) void gemm_k(
    const short* __restrict__ A, const short* __restrict__ W,
    short* __restrict__ Qr, short* __restrict__ Kr, short* __restrict__ Vt,
    float* __restrict__ Of,
    const float* __restrict__ cosT, const float* __restrict__ sinT, int fused) {
  // SH: A buffers 3x4096 at 0, B buffers 3x4096 at 12288 (48 KB total).
  // Epilogue V^T transpose reuses SH[0..17407].
  __shared__ short SH[24576];
  const int tid = threadIdx.x;
  const int lane = tid & 63, wid = tid >> 6;
  const int quad = lane >> 4, l15 = lane & 15;
  const int sw4 = (l15 ^ (l15 >> 2)) & 3;    // lane-uniform read swizzle
  const int bid = blockIdx.x;
  const int m0 = ((bid & 7) * 4 + ((bid >> 3) & 3)) * 128;
  const int n0 = (bid >> 5) * 128;
  const int wm = (wid & 1) * 64, wn = (wid >> 1) * 64;

  f32x4 acc[4][4] = {};

  // staging: 512 16B-chunks per matrix per tile; thread -> chunks tid, tid+256
  // chunk i: row i>>2, phys chunk i&3 holds src k-chunk (i&3)^((row^(row>>2))&3)
  const int r0 = tid >> 2;
  const int c0 = (((tid & 3) ^ ((r0 ^ (r0 >> 2)) & 3))) << 3;   // shorts
  const short* Ap = A + (size_t)(m0 + r0) * ND + c0;
  const short* Wp = W + (size_t)(n0 + r0) * ND + c0;

  auto stage = [&](int b) {                    // stages current k, advances
    async16(Ap, SH + b * 4096 + tid * 8);
    async16(Ap + (size_t)64 * ND, SH + b * 4096 + (tid + 256) * 8);
    async16(Wp, SH + 12288 + b * 4096 + tid * 8);
    async16(Wp + (size_t)64 * ND, SH + 12288 + b * 4096 + (tid + 256) * 8);
    Ap += 32; Wp += 32;
  };

  const int co = (quad ^ sw4) << 3;
  auto kiter = [&](int cur, int nb, bool dostage, bool last) {
    if (!last) pipe_barrier4(); else pipe_barrier0();
    if (dostage) stage(nb);
    const short* Ac = SH + cur * 4096;
    const short* Bc = SH + 12288 + cur * 4096;
    bf16x8 af[4], bf[4];
#pragma unroll
    for (int i = 0; i < 4; i++)
      af[i] = *(const bf16x8*)(Ac + (wm + i * 16 + l15) * 32 + co);
#pragma unroll
    for (int j = 0; j < 4; j++)
      bf[j] = *(const bf16x8*)(Bc + (wn + j * 16 + l15) * 32 + co);
#pragma unroll
    for (int i = 0; i < 4; i++)
#pragma unroll
      for (int j = 0; j < 4; j++)
        acc[i][j] = mfma16(af[i], bf[j], acc[i][j]);
  };

  stage(0); stage(1);
  for (int base = 0; base < 30; base += 3) {   // tiles 0..29
    kiter(0, 2, true, false);
    kiter(1, 0, true, false);
    kiter(2, 1, base + 2 < 30, false);         // stop staging after tile 31
  }
  kiter(0, 2, false, false);                   // tile 30
  kiter(1, 0, false, true);                    // tile 31 (full drain)

  // epilogue — C layout: col = lane&15, row = quad*4 + reg
  const int seg = fused ? (n0 >> 10) : 0;   // fused: 0=Q 1=K 2=V
  if (fused && seg == 2) {
    // V^T: transpose through LDS (pitch 136), then coalesced 16B stores
    __syncthreads();                     // everyone done reading staging
#pragma unroll
    for (int i = 0; i < 4; i++) {
      const int mm = wm + i * 16 + quad * 4;
#pragma unroll
      for (int j = 0; j < 4; j++) {
        const int nn = wn + j * 16 + l15;
#pragma unroll
        for (int r = 0; r < 4; r++)
          SH[nn * 136 + mm + r] = f2b(acc[i][j][r]);
      }
    }
    __syncthreads();
    const int b = m0 >> 11, s0 = m0 & (NS - 1);
#pragma unroll
    for (int c = 0; c < 8; c++) {
      const int idx = c * 256 + tid;        // 0..2047
      const int nn = idx >> 4, ch = idx & 15;
      const int gnn = (n0 & 1023) + nn;
      const int h = gnn >> 6, d = gnn & 63;
      *(bf16x8*)(Vt + (size_t)((b * NH + h) * NDK + d) * NS + s0 + ch * 8) =
          *(const bf16x8*)(SH + nn * 136 + ch * 8);
    }
    return;
  }

  short* QK = (seg == 0) ? Qr : Kr;
  // Q gets 1/sqrt(DK) * log2(e) folded in (attention uses exp2)
  const float qsc = (fused && seg == 0) ? 0.125f * 1.44269504f : 1.0f;
#pragma unroll
  for (int i = 0; i < 4; i++) {
    const int gmB = m0 + wm + i * 16 + quad * 4;
#pragma unroll
    for (int j = 0; j < 4; j++) {
      const int gn = n0 + wn + j * 16 + l15;
      f32x4 v = acc[i][j];
      if (!fused) {
#pragma unroll
        for (int r = 0; r < 4; r++)
          Of[(size_t)(gmB + r) * ND + gn] = v[r];
      } else {
        const int nn = gn & 1023;
        const int h = nn >> 6, d = nn & 63, jj = d >> 1;
#pragma unroll
        for (int r = 0; r < 4; r++) {
          const int t = gmB + r, b = t >> 11, s = t & (NS - 1);
          const float xv = v[r];
          const float pv = __shfl_xor(xv, 1);   // partner column (d^1)
          const float c = cosT[s * 32 + jj], sn = sinT[s * 32 + jj];
          const float o = (d & 1) ? (pv * sn + xv * c)
                                  : (xv * c - pv * sn);
          QK[(size_t)((b * NH + h) * NS + s) * NDK + d] = f2b(o * qsc);
        }
      }
    }
  }
}

// ---------------------------------------------------------------------------
// Flash attention, S^T formulation, fixed-max softmax, balanced pairing
// (block = q-tiles p and 31-p -> exactly 33 key-tiles). 512 blocks x 256 thr
// (4 waves x 16 q), 64-key tiles.
// THIS ROUND: K is read DIRECTLY from global (L1/L2-resident, per-lane
// coalesced dwordx4, register double-buffered one tile ahead) instead of
// LDS-staged — moves 32 KB/block-phase of QK fragment traffic off the
// saturated LDS pipe onto the parallel TCP path and deletes K staging.
// V stays LDS-staged (double-buffered); V-fragment ds_reads are hoisted
// above the P-write drain so their latency hides under the exp/pack VALU.
// PROBE fold retained: bid &= 511 (launch grid 2048 = 4 idempotent copies).
// ---------------------------------------------------------------------------
__global__ __launch_bounds__(256, 2) void attn_k(
    const short* __restrict__ Q, const short* __restrict__ K,
    const short* __restrict__ Vt, short* __restrict__ O) {
  __shared__ short Vs[2][64 * 64];   // [d][key], chunk-swizzled
  __shared__ short Ps[4 * 16 * 72];  // per-wave P[q][key], pitch 72
  const int tid = threadIdx.x, lane = tid & 63, wid = tid >> 6;
  const int quad = lane >> 4, l15 = lane & 15;
  const int sw = l15 & 7;
  const int bid = blockIdx.x & 511;  // probe fold
  const int bh = (bid & 7) | (((bid >> 3) & 3) << 3);
  const int p = bid >> 5;            // 0..15
  const int qtA = 31 - p, qtB = p;   // paired q-tiles (64 q each)
  const short* Qh = Q + (size_t)bh * NS * NDK;
  const short* Kh = K + (size_t)bh * NS * NDK;
  const short* Vh = Vt + (size_t)bh * NDK * NS;

  const int qwA = qtA * 64 + wid * 16;
  const int qwB = qtB * 64 + wid * 16;

  // Q B-fragments for both passes (Q pre-scaled by 0.125*log2e)
  bf16x8 qfA[2], qfB[2];
#pragma unroll
  for (int h = 0; h < 2; h++) {
    qfA[h] = *(const bf16x8*)(Qh + (size_t)(qwA + l15) * NDK + h * 32 + quad * 8);
    qfB[h] = *(const bf16x8*)(Qh + (size_t)(qwB + l15) * NDK + h * 32 + quad * 8);
  }

  f32x4 oA[4] = {}, oB[4] = {};
  float lpA = 0.f, lpB = 0.f;
  short* Pw = Ps + wid * (16 * 72);

  // V staging: 512 chunks; thread -> chunks tid and tid+256 (d-rows 0..63)
  const int kr0 = tid >> 3;
  const int sk0 = ((tid & 7) ^ (kr0 & 7)) << 3;
  const int kr1 = kr0 + 32;
  const int sk1 = ((tid & 7) ^ (kr1 & 7)) << 3;
  const int ntA = qtA + 1;             // tiles in pass A (ntot = 33 always)

  auto k0of = [&](int st) { return (st < ntA) ? st * 64 : (st - ntA) * 64; };

  auto stage = [&](int st, int b) {    // stage V for key-tile index st
    const int k0 = k0of(st);
    async16(Vh + (size_t)kr0 * NS + k0 + sk0, Vs[b] + tid * 8);
    async16(Vh + (size_t)kr1 * NS + k0 + sk1, Vs[b] + (tid + 256) * 8);
  };

  // K fragments for tile st, direct from global into registers.
  // kf[2f] = K[key=f*16+l15][d = quad*8 .. +7], kf[2f+1] = same at d+32.
  const short* Kb0 = Kh + (size_t)l15 * NDK + quad * 8;
  auto loadK = [&](bf16x8* kf, int st) {
    const short* Kb = Kb0 + (size_t)k0of(st) * NDK;
#pragma unroll
    for (int f = 0; f < 4; f++) {
      kf[2 * f]     = *(const bf16x8*)(Kb + (size_t)f * 16 * NDK);
      kf[2 * f + 1] = *(const bf16x8*)(Kb + (size_t)f * 16 * NDK + 32);
    }
  };

  // one tile of 64 keys against this wave's 16 queries (cur is literal)
  auto tile = [&](int cur, const bf16x8* kf, const bf16x8* qf, f32x4* o,
                  float& lp, bool diag) {
    f32x4 sc[4];
#pragma unroll
    for (int f = 0; f < 4; f++) {
      f32x4 z = {};
      z = mfma16(kf[2 * f], qf[0], z);
      z = mfma16(kf[2 * f + 1], qf[1], z);
      sc[f] = z;
    }
    if (diag) {  // q-tile == key-tile: local key vs local query wid*16+l15
      const int mq = wid * 16 + l15;
#pragma unroll
      for (int f = 0; f < 4; f++)
#pragma unroll
        for (int r = 0; r < 4; r++)
          sc[f][r] = (f * 16 + quad * 4 + r <= mq) ? sc[f][r] : -1e30f;
    }
    // P = exp2(score), per-lane l accumulation (raw v_exp_f32)
#pragma unroll
    for (int f = 0; f < 4; f++)
#pragma unroll
      for (int r = 0; r < 4; r++) {
        const float e = fast_exp2(sc[f][r]);
        sc[f][r] = e;
        lp += e;
      }
    // hoist V fragments: issue ds_reads now so latency hides under packing
    bf16x8 vf[2][4];
#pragma unroll
    for (int kc = 0; kc < 2; kc++)
#pragma unroll
      for (int nd = 0; nd < 4; nd++)
        vf[kc][nd] = *(const bf16x8*)(
            Vs[cur] + (((nd * 16 + l15) * 8 + ((kc * 4 + quad) ^ sw)) * 8));
    // write P[q=l15][key] as packed pairs (one b64 per frag)
#pragma unroll
    for (int f = 0; f < 4; f++) {
      unsigned d0 = f2b2(sc[f][0], sc[f][1]);
      unsigned d1 = f2b2(sc[f][2], sc[f][3]);
      uint2 pw; pw.x = d0; pw.y = d1;
      *(uint2*)(Pw + l15 * 72 + f * 16 + quad * 4) = pw;
    }
    asm volatile("s_waitcnt lgkmcnt(0)" ::: "memory");
    // O += P V
#pragma unroll
    for (int kc = 0; kc < 2; kc++) {
      bf16x8 pf = *(const bf16x8*)(Pw + l15 * 72 + kc * 32 + quad * 8);
#pragma unroll
      for (int nd = 0; nd < 4; nd++)
        o[nd] = mfma16(pf, vf[kc][nd], o[nd]);
    }
  };

  auto dotile = [&](int tt, int cur, const bf16x8* kf) {
    if (tt < ntA) tile(cur, kf, qfA, oA, lpA, tt == ntA - 1);
    else          tile(cur, kf, qfB, oB, lpB, tt == 32);
  };

  bf16x8 kf0[8], kf1[8];
  loadK(kf0, 0);
  stage(0, 0);
  __syncthreads();

  for (int tt = 0; tt < 32; tt += 2) {
    stage(tt + 1, 1);
    loadK(kf1, tt + 1);                // overlaps with dotile(tt)
    dotile(tt, 0, kf0);
    __syncthreads();
    stage(tt + 2, 0);                  // tt+2 <= 32, always valid
    loadK(kf0, tt + 2);
    dotile(tt + 1, 1, kf1);
    __syncthreads();
  }
  dotile(32, 0, kf0);                  // final tile (buffer 0)

  // final l reductions and epilogues for both passes
  const int b = bh >> 4, h = bh & (NH - 1);
  lpA += __shfl_xor(lpA, 16); lpA += __shfl_xor(lpA, 32);
  lpB += __shfl_xor(lpB, 16); lpB += __shfl_xor(lpB, 32);
  const float liA = 1.0f / lpA, liB = 1.0f / lpB;
#pragma unroll
  for (int r = 0; r < 4; r++) {
    const float lrA = __shfl(liA, quad * 4 + r);
    const float lrB = __shfl(liB, quad * 4 + r);
    const int qA = qwA + quad * 4 + r, qB = qwB + quad * 4 + r;
#pragma unroll
    for (int nd = 0; nd < 4; nd++) {
      O[(size_t)(b * NS + qA) * ND + h * NDK + nd * 16 + l15] =
          f2b(oA[nd][r] * lrA);
      O[(size_t)(b * NS + qB) * ND + h * NDK + nd * 16 + l15] =
          f2b(oB[nd][r] * lrB);
    }
  }
}

// ---------------------------------------------------------------------------
extern "C" void kernel_launch(void* const* d_in, const int* in_sizes, int n_in,
                              void* d_out, int out_size, void* d_ws, size_t ws_size,
                              hipStream_t stream) {
  const float* x  = (const float*)d_in[0];
  const int* pos  = (const int*)d_in[1];
  const float* Wq = (const float*)d_in[2];
  const float* Wk = (const float*)d_in[3];
  const float* Wv = (const float*)d_in[4];
  const float* Wo = (const float*)d_in[5];
  float* out = (float*)d_out;

  // workspace (shorts): xb | wq | wk | wv | wo | Qr | Kr | Vt | tables
  short* xb  = (short*)d_ws;          // reused as attn output O
  short* wqb = xb + 4194304;
  short* wkb = wqb + 1048576;
  short* wvb = wkb + 1048576;
  short* wob = wvb + 1048576;
  short* Qr  = wob + 1048576;
  short* Kr  = Qr + 4194304;
  short* Vt  = Kr + 4194304;
  float* cosT = (float*)(Vt + 4194304);
  float* sinT = cosT + NS * 32;

  prep_k<<<dim3(2048), dim3(256), 0, stream>>>(x, Wq, Wk, Wv, Wo, pos,
                                               xb, wqb, wkb, wvb, wob, cosT, sinT);
  // fused QKV: W = [Wq;Wk;Wv] rows (contiguous in ws), N=3072
  gemm_k<<<dim3(768), dim3(256), 0, stream>>>(xb, wqb, Qr, Kr, Vt, nullptr,
                                              cosT, sinT, 1);
  // MEASUREMENT: single x4-fold launch (grid 2048, bid&=511) — computes the
  // real result 4x idempotently AND surfaces true attn counters in top-5.
  attn_k<<<dim3(2048), dim3(256), 0, stream>>>(Qr, Kr, Vt, xb);
  gemm_k<<<dim3(256), dim3(256), 0, stream>>>(xb, wob, nullptr, nullptr, nullptr,
                                              out, cosT, sinT, 0);
}

// Round 7
// 165.641 us; speedup vs baseline: 2.3321x; 2.3321x over previous
//
#include <hip/hip_runtime.h>
#include <hip/hip_bf16.h>

// Problem constants (B,S,D,H,DK) = (2,2048,1024,16,64), fp32 in/out.
#define NB 2
#define NS 2048
#define ND 1024
#define NH 16
#define NDK 64

typedef __attribute__((ext_vector_type(4))) float f32x4;
typedef __attribute__((ext_vector_type(8))) short bf16x8;
typedef __attribute__((ext_vector_type(4))) short bf16x4;

__device__ __forceinline__ f32x4 mfma16(bf16x8 a, bf16x8 b, f32x4 c) {
  return __builtin_amdgcn_mfma_f32_16x16x32_bf16(a, b, c, 0, 0, 0);
}

// async global->LDS, 16B per lane (dest = wave-uniform base + lane*16)
__device__ __forceinline__ void async16(const void* g, void* l) {
  __builtin_amdgcn_global_load_lds(
      (const __attribute__((address_space(1))) unsigned int*)g,
      (__attribute__((address_space(3))) unsigned int*)l, 16, 0, 0);
}

// fp32 -> bf16 RNE
__device__ __forceinline__ short f2b(float f) {
  union { float f; unsigned u; } v;
  v.f = f;
  unsigned r = v.u + 0x7FFFu + ((v.u >> 16) & 1u);
  return (short)(r >> 16);
}

// packed fp32x2 -> bf16x2 (RNE) via v_perm_b32.
// NOTE (R6 post-mortem): v_cvt_pk_bf16_f32 inline asm here FAILED correctness
// (absmax 0.314, run-varying) — do not substitute it for this helper.
__device__ __forceinline__ unsigned f2b2(float a, float b) {
  unsigned ua = __float_as_uint(a), ub = __float_as_uint(b);
  ua = ua + 0x7FFFu + ((ua >> 16) & 1u);
  ub = ub + 0x7FFFu + ((ub >> 16) & 1u);
  return __builtin_amdgcn_perm(ub, ua, 0x07060302);  // {ua.hi16, ub.hi16}
}

// raw v_exp_f32 — inputs here are either in [-40, 40] or -1e30 (masked -> 0),
// so the OCML denorm-fixup sequence exp2f expands to is unnecessary.
__device__ __forceinline__ float fast_exp2(float x) {
#if __has_builtin(__builtin_amdgcn_exp2f)
  return __builtin_amdgcn_exp2f(x);
#else
  return exp2f(x);
#endif
}

// pipeline barriers: wait only the N-oldest outstanding staging loads, then
// barrier (per-thread own-loads-complete + barrier => whole tile complete).
__device__ __forceinline__ void pipe_barrier4() {
  asm volatile("s_waitcnt vmcnt(4)\n\ts_barrier" ::: "memory");
}
__device__ __forceinline__ void pipe_barrier0() {
  asm volatile("s_waitcnt vmcnt(0)\n\ts_barrier" ::: "memory");
}

// ---------------------------------------------------------------------------
// prep: cast x and weights to bf16 (float4-vectorized), RoPE tables [S][32]
// ---------------------------------------------------------------------------
__global__ void prep_k(const float* __restrict__ x,
                       const float* __restrict__ Wq, const float* __restrict__ Wk,
                       const float* __restrict__ Wv, const float* __restrict__ Wo,
                       const int* __restrict__ pos,
                       short* __restrict__ xb,
                       short* __restrict__ wqb, short* __restrict__ wkb,
                       short* __restrict__ wvb, short* __restrict__ wob,
                       float* __restrict__ cosT, float* __restrict__ sinT) {
  const int stride = gridDim.x * blockDim.x;
  const int tid = blockIdx.x * blockDim.x + threadIdx.x;
  const float4* x4 = (const float4*)x;
  for (int i = tid; i < NB * NS * ND / 4; i += stride) {
    float4 v = x4[i];
    bf16x4 p; p[0] = f2b(v.x); p[1] = f2b(v.y); p[2] = f2b(v.z); p[3] = f2b(v.w);
    *(bf16x4*)(xb + i * 4) = p;
  }
  const float4* q4 = (const float4*)Wq; const float4* k4 = (const float4*)Wk;
  const float4* v4 = (const float4*)Wv; const float4* o4 = (const float4*)Wo;
  for (int i = tid; i < ND * ND / 4; i += stride) {
    float4 a = q4[i], b = k4[i], c = v4[i], d = o4[i];
    bf16x4 pa, pb, pc, pd;
    pa[0]=f2b(a.x); pa[1]=f2b(a.y); pa[2]=f2b(a.z); pa[3]=f2b(a.w);
    pb[0]=f2b(b.x); pb[1]=f2b(b.y); pb[2]=f2b(b.z); pb[3]=f2b(b.w);
    pc[0]=f2b(c.x); pc[1]=f2b(c.y); pc[2]=f2b(c.z); pc[3]=f2b(c.w);
    pd[0]=f2b(d.x); pd[1]=f2b(d.y); pd[2]=f2b(d.z); pd[3]=f2b(d.w);
    *(bf16x4*)(wqb + i*4) = pa; *(bf16x4*)(wkb + i*4) = pb;
    *(bf16x4*)(wvb + i*4) = pc; *(bf16x4*)(wob + i*4) = pd;
  }
  for (int i = tid; i < NS * 32; i += stride) {
    const int s = i >> 5, j = i & 31;
    const float inv = 1.0f / powf(10000.0f, (float)j * (1.0f / 32.0f));
    const float a = (float)pos[s] * inv;
    cosT[i] = cosf(a);
    sinT[i] = sinf(a);
  }
}

// ---------------------------------------------------------------------------
// GEMM: C[m,n] = sum_k A[m,k]*W[n,k];  M=4096, K=1024, bf16 MFMA.
// m97 wave shape: 256 threads, 4 waves (2x2), each wave 4x4 frags of 16x16
// (16 MFMA per 8 ds_read_b128). 128x128 tile, BK=32, TRIPLE-buffered with
// vmcnt(4) pipeline barriers (loads get ~2 compute phases), unrolled x3 so
// the buffer index is compile-time. 48 KB LDS (reused by V^T transpose).
// XCD decode: xcd=id&7 owns 4 m-panels; n streams (A stays L2-resident).
// ---------------------------------------------------------------------------
__global__ __launch_bounds__(256, 3) void gemm_k(
    const short* __restrict__ A, const short* __restrict__ W,
    short* __restrict__ Qr, short* __restrict__ Kr, short* __restrict__ Vt,
    float* __restrict__ Of,
    const float* __restrict__ cosT, const float* __restrict__ sinT, int fused) {
  // SH: A buffers 3x4096 at 0, B buffers 3x4096 at 12288 (48 KB total).
  // Epilogue V^T transpose reuses SH[0..17407].
  __shared__ short SH[24576];
  const int tid = threadIdx.x;
  const int lane = tid & 63, wid = tid >> 6;
  const int quad = lane >> 4, l15 = lane & 15;
  const int sw4 = (l15 ^ (l15 >> 2)) & 3;    // lane-uniform read swizzle
  const int bid = blockIdx.x;
  const int m0 = ((bid & 7) * 4 + ((bid >> 3) & 3)) * 128;
  const int n0 = (bid >> 5) * 128;
  const int wm = (wid & 1) * 64, wn = (wid >> 1) * 64;

  f32x4 acc[4][4] = {};

  // staging: 512 16B-chunks per matrix per tile; thread -> chunks tid, tid+256
  // chunk i: row i>>2, phys chunk i&3 holds src k-chunk (i&3)^((row^(row>>2))&3)
  const int r0 = tid >> 2;
  const int c0 = (((tid & 3) ^ ((r0 ^ (r0 >> 2)) & 3))) << 3;   // shorts
  const short* Ap = A + (size_t)(m0 + r0) * ND + c0;
  const short* Wp = W + (size_t)(n0 + r0) * ND + c0;

  auto stage = [&](int b) {                    // stages current k, advances
    async16(Ap, SH + b * 4096 + tid * 8);
    async16(Ap + (size_t)64 * ND, SH + b * 4096 + (tid + 256) * 8);
    async16(Wp, SH + 12288 + b * 4096 + tid * 8);
    async16(Wp + (size_t)64 * ND, SH + 12288 + b * 4096 + (tid + 256) * 8);
    Ap += 32; Wp += 32;
  };

  const int co = (quad ^ sw4) << 3;
  auto kiter = [&](int cur, int nb, bool dostage, bool last) {
    if (!last) pipe_barrier4(); else pipe_barrier0();
    if (dostage) stage(nb);
    const short* Ac = SH + cur * 4096;
    const short* Bc = SH + 12288 + cur * 4096;
    bf16x8 af[4], bf[4];
#pragma unroll
    for (int i = 0; i < 4; i++)
      af[i] = *(const bf16x8*)(Ac + (wm + i * 16 + l15) * 32 + co);
#pragma unroll
    for (int j = 0; j < 4; j++)
      bf[j] = *(const bf16x8*)(Bc + (wn + j * 16 + l15) * 32 + co);
#pragma unroll
    for (int i = 0; i < 4; i++)
#pragma unroll
      for (int j = 0; j < 4; j++)
        acc[i][j] = mfma16(af[i], bf[j], acc[i][j]);
  };

  stage(0); stage(1);
  for (int base = 0; base < 30; base += 3) {   // tiles 0..29
    kiter(0, 2, true, false);
    kiter(1, 0, true, false);
    kiter(2, 1, base + 2 < 30, false);         // stop staging after tile 31
  }
  kiter(0, 2, false, false);                   // tile 30
  kiter(1, 0, false, true);                    // tile 31 (full drain)

  // epilogue — C layout: col = lane&15, row = quad*4 + reg
  const int seg = fused ? (n0 >> 10) : 0;   // fused: 0=Q 1=K 2=V
  if (fused && seg == 2) {
    // V^T: transpose through LDS (pitch 136), then coalesced 16B stores
    __syncthreads();                     // everyone done reading staging
#pragma unroll
    for (int i = 0; i < 4; i++) {
      const int mm = wm + i * 16 + quad * 4;
#pragma unroll
      for (int j = 0; j < 4; j++) {
        const int nn = wn + j * 16 + l15;
#pragma unroll
        for (int r = 0; r < 4; r++)
          SH[nn * 136 + mm + r] = f2b(acc[i][j][r]);
      }
    }
    __syncthreads();
    const int b = m0 >> 11, s0 = m0 & (NS - 1);
#pragma unroll
    for (int c = 0; c < 8; c++) {
      const int idx = c * 256 + tid;        // 0..2047
      const int nn = idx >> 4, ch = idx & 15;
      const int gnn = (n0 & 1023) + nn;
      const int h = gnn >> 6, d = gnn & 63;
      *(bf16x8*)(Vt + (size_t)((b * NH + h) * NDK + d) * NS + s0 + ch * 8) =
          *(const bf16x8*)(SH + nn * 136 + ch * 8);
    }
    return;
  }

  short* QK = (seg == 0) ? Qr : Kr;
  // Q gets 1/sqrt(DK) * log2(e) folded in (attention uses exp2)
  const float qsc = (fused && seg == 0) ? 0.125f * 1.44269504f : 1.0f;
#pragma unroll
  for (int i = 0; i < 4; i++) {
    const int gmB = m0 + wm + i * 16 + quad * 4;
#pragma unroll
    for (int j = 0; j < 4; j++) {
      const int gn = n0 + wn + j * 16 + l15;
      f32x4 v = acc[i][j];
      if (!fused) {
#pragma unroll
        for (int r = 0; r < 4; r++)
          Of[(size_t)(gmB + r) * ND + gn] = v[r];
      } else {
        const int nn = gn & 1023;
        const int h = nn >> 6, d = nn & 63, jj = d >> 1;
#pragma unroll
        for (int r = 0; r < 4; r++) {
          const int t = gmB + r, b = t >> 11, s = t & (NS - 1);
          const float xv = v[r];
          const float pv = __shfl_xor(xv, 1);   // partner column (d^1)
          const float c = cosT[s * 32 + jj], sn = sinT[s * 32 + jj];
          const float o = (d & 1) ? (pv * sn + xv * c)
                                  : (xv * c - pv * sn);
          QK[(size_t)((b * NH + h) * NS + s) * NDK + d] = f2b(o * qsc);
        }
      }
    }
  }
}

// ---------------------------------------------------------------------------
// Flash attention, S^T formulation, fixed-max softmax.
// One q-tile (64 q) per block, grid 1024 = 32 bh x 32 qt, dispatched
// LONGEST-FIRST (qt = 31 - bid>>5) -> 3 blocks/CU resident (42 KB LDS)
// instead of 2 with the old paired-512 grid; short blocks fill the drain.
// K in LDS (R5's direct-global K regressed 2.2x: latency-bound). V-fragment
// ds_reads hoisted above the P-write drain (R5-verified). P pack via f2b2
// (R6's v_cvt_pk_bf16_f32 asm FAILED correctness — reverted).
// 256 thr = 4 waves x 16 q, 64-key tiles, XOR-swizzled LDS, double-buffered,
// compile-time buffer indices.
// ---------------------------------------------------------------------------
__global__ __launch_bounds__(256, 3) void attn_k(
    const short* __restrict__ Q, const short* __restrict__ K,
    const short* __restrict__ Vt, short* __restrict__ O) {
  __shared__ short Ks[2][64 * 64];   // [key][d], chunk-swizzled
  __shared__ short Vs[2][64 * 64];   // [d][key], chunk-swizzled
  __shared__ short Ps[4 * 16 * 72];  // per-wave P[q][key], pitch 72
  const int tid = threadIdx.x, lane = tid & 63, wid = tid >> 6;
  const int quad = lane >> 4, l15 = lane & 15;
  const int sw = l15 & 7;
  const int bid = blockIdx.x;
  const int bh = bid & 31;           // same-bh blocks stride 32 -> same XCD
  const int qt = 31 - (bid >> 5);    // longest blocks dispatch first
  const int nt = qt + 1;             // key-tiles for this q-tile (causal)
  const short* Qh = Q + (size_t)bh * NS * NDK;
  const short* Kh = K + (size_t)bh * NS * NDK;
  const short* Vh = Vt + (size_t)bh * NDK * NS;

  const int qw = qt * 64 + wid * 16;

  // Q B-fragments (Q pre-scaled by 0.125*log2e)
  bf16x8 qf[2];
#pragma unroll
  for (int h = 0; h < 2; h++)
    qf[h] = *(const bf16x8*)(Qh + (size_t)(qw + l15) * NDK + h * 32 + quad * 8);

  f32x4 o[4] = {};
  float lp = 0.f;
  short* Pw = Ps + wid * (16 * 72);

  // staging: 512 chunks each for Ks/Vs; thread -> chunks tid and tid+256
  const int kr0 = tid >> 3;
  const int sk0 = ((tid & 7) ^ (kr0 & 7)) << 3;
  const int kr1 = kr0 + 32;
  const int sk1 = ((tid & 7) ^ (kr1 & 7)) << 3;

  auto stage = [&](int st, int b) {    // stage key-tile st
    const int k0 = st * 64;
    async16(Kh + (size_t)(k0 + kr0) * NDK + sk0, Ks[b] + tid * 8);
    async16(Kh + (size_t)(k0 + kr1) * NDK + sk1, Ks[b] + (tid + 256) * 8);
    async16(Vh + (size_t)kr0 * NS + k0 + sk0, Vs[b] + tid * 8);
    async16(Vh + (size_t)kr1 * NS + k0 + sk1, Vs[b] + (tid + 256) * 8);
  };

  // one tile of 64 keys against this wave's 16 queries (cur is literal)
  auto tile = [&](int cur, bool diag) {
    f32x4 sc[4];
#pragma unroll
    for (int f = 0; f < 4; f++) {
      const int row = (f * 16 + l15) * 8;
      bf16x8 a0 = *(const bf16x8*)(Ks[cur] + (row + (quad ^ sw)) * 8);
      bf16x8 a1 = *(const bf16x8*)(Ks[cur] + (row + ((4 + quad) ^ sw)) * 8);
      f32x4 z = {};
      z = mfma16(a0, qf[0], z);
      z = mfma16(a1, qf[1], z);
      sc[f] = z;
    }
    if (diag) {  // q-tile == key-tile: local key vs local query wid*16+l15
      const int mq = wid * 16 + l15;
#pragma unroll
      for (int f = 0; f < 4; f++)
#pragma unroll
        for (int r = 0; r < 4; r++)
          sc[f][r] = (f * 16 + quad * 4 + r <= mq) ? sc[f][r] : -1e30f;
    }
    // P = exp2(score), per-lane l accumulation (raw v_exp_f32)
#pragma unroll
    for (int f = 0; f < 4; f++)
#pragma unroll
      for (int r = 0; r < 4; r++) {
        const float e = fast_exp2(sc[f][r]);
        sc[f][r] = e;
        lp += e;
      }
    // hoist V fragments: issue ds_reads now so latency hides under packing
    bf16x8 vf[2][4];
#pragma unroll
    for (int kc = 0; kc < 2; kc++)
#pragma unroll
      for (int nd = 0; nd < 4; nd++)
        vf[kc][nd] = *(const bf16x8*)(
            Vs[cur] + (((nd * 16 + l15) * 8 + ((kc * 4 + quad) ^ sw)) * 8));
    // write P[q=l15][key] as packed pairs (one b64 per frag)
#pragma unroll
    for (int f = 0; f < 4; f++) {
      uint2 pw;
      pw.x = f2b2(sc[f][0], sc[f][1]);
      pw.y = f2b2(sc[f][2], sc[f][3]);
      *(uint2*)(Pw + l15 * 72 + f * 16 + quad * 4) = pw;
    }
    asm volatile("s_waitcnt lgkmcnt(0)" ::: "memory");
    // O += P V
#pragma unroll
    for (int kc = 0; kc < 2; kc++) {
      bf16x8 pf = *(const bf16x8*)(Pw + l15 * 72 + kc * 32 + quad * 8);
#pragma unroll
      for (int nd = 0; nd < 4; nd++)
        o[nd] = mfma16(pf, vf[kc][nd], o[nd]);
    }
  };

  stage(0, 0);
  __syncthreads();

  int tt = 0;
  for (; tt + 2 < nt; tt += 2) {
    stage(tt + 1, 1);
    tile(0, false);                    // tt (tt+2<nt => tt < nt-2, not diag)
    __syncthreads();
    stage(tt + 2, 0);
    tile(1, false);                    // tt+1 < nt-1, never diag in loop
    __syncthreads();
  }
  if (tt + 1 < nt) {                   // nt even: two tiles left (tt, tt+1)
    stage(tt + 1, 1);
    tile(0, false);
    __syncthreads();
    tile(1, true);                     // tt+1 == nt-1
  } else {                             // nt odd: one tile left (tt == nt-1)
    tile(0, true);
  }

  // final l reduction and epilogue
  const int b = bh >> 4, h = bh & (NH - 1);
  lp += __shfl_xor(lp, 16); lp += __shfl_xor(lp, 32);
  const float li = 1.0f / lp;
#pragma unroll
  for (int r = 0; r < 4; r++) {
    const float lr = __shfl(li, quad * 4 + r);
    const int q = qw + quad * 4 + r;
#pragma unroll
    for (int nd = 0; nd < 4; nd++)
      O[(size_t)(b * NS + q) * ND + h * NDK + nd * 16 + l15] =
          f2b(o[nd][r] * lr);
  }
}

// ---------------------------------------------------------------------------
extern "C" void kernel_launch(void* const* d_in, const int* in_sizes, int n_in,
                              void* d_out, int out_size, void* d_ws, size_t ws_size,
                              hipStream_t stream) {
  const float* x  = (const float*)d_in[0];
  const int* pos  = (const int*)d_in[1];
  const float* Wq = (const float*)d_in[2];
  const float* Wk = (const float*)d_in[3];
  const float* Wv = (const float*)d_in[4];
  const float* Wo = (const float*)d_in[5];
  float* out = (float*)d_out;

  // workspace (shorts): xb | wq | wk | wv | wo | Qr | Kr | Vt | tables
  short* xb  = (short*)d_ws;          // reused as attn output O
  short* wqb = xb + 4194304;
  short* wkb = wqb + 1048576;
  short* wvb = wkb + 1048576;
  short* wob = wvb + 1048576;
  short* Qr  = wob + 1048576;
  short* Kr  = Qr + 4194304;
  short* Vt  = Kr + 4194304;
  float* cosT = (float*)(Vt + 4194304);
  float* sinT = cosT + NS * 32;

  prep_k<<<dim3(2048), dim3(256), 0, stream>>>(x, Wq, Wk, Wv, Wo, pos,
                                               xb, wqb, wkb, wvb, wob, cosT, sinT);
  // fused QKV: W = [Wq;Wk;Wv] rows (contiguous in ws), N=3072
  gemm_k<<<dim3(768), dim3(256), 0, stream>>>(xb, wqb, Qr, Kr, Vt, nullptr,
                                              cosT, sinT, 1);
  // attn: 1 q-tile per block, longest-first (grid 1024 = 32 bh x 32 qt)
  attn_k<<<dim3(1024), dim3(256), 0, stream>>>(Qr, Kr, Vt, xb);
  gemm_k<<<dim3(256), dim3(256), 0, stream>>>(xb, wob, nullptr, nullptr, nullptr,
                                              out, cosT, sinT, 0);
}